// Round 2
// baseline (420.200 us; speedup 1.0000x reference)
//
#include <hip/hip_runtime.h>
#include <stdint.h>

// Problem constants (fixed by the reference setup)
#define BB 2
#define NN 10000
#define EE 100000
#define FF 512
#define HH 512
constexpr int M_ROWS = BB * NN;   // 20000 GEMM rows
constexpr int BE     = BB * EE;   // 200000 edges total

typedef __attribute__((ext_vector_type(8))) short short8;   // 8 bf16 (4 VGPRs)
typedef __attribute__((ext_vector_type(4))) float f32x4;    // MFMA accumulator

__device__ __forceinline__ float b2f(unsigned short u) {
    union { unsigned int i; float f; } v; v.i = ((unsigned int)u) << 16; return v.f;
}
__device__ __forceinline__ unsigned short f2b(float f) {   // round-to-nearest-even
    unsigned int x = __float_as_uint(f);
    x += 0x7fffu + ((x >> 16) & 1u);
    return (unsigned short)(x >> 16);
}

// ---------------- dtype detection ----------------
// If node_features is f32, even-index ushorts are low mantissa halves (uniform bits);
// if bf16 N(0,1), every ushort has exponent field in ~[110,134]. Count and decide.
// flag = 1 -> inputs/outputs are float32; flag = 0 -> bfloat16.
__global__ void detect_k(const unsigned short* __restrict__ x, int* __restrict__ flag) {
    if (threadIdx.x == 0 && blockIdx.x == 0) {
        int good = 0;
        for (int i = 0; i < 128; i++) {
            unsigned short u = x[2 * i];
            int e = (u >> 7) & 0xFF;
            if (e >= 100 && e <= 140) good++;
        }
        *flag = (good < 96) ? 1 : 0;
    }
}

// ---------------- canonicalize X to bf16 ----------------
__global__ __launch_bounds__(256) void convertX_k(const void* __restrict__ Xraw,
                                                  const int* __restrict__ flag,
                                                  unsigned short* __restrict__ Xb, int n) {
    int i = blockIdx.x * 256 + threadIdx.x;
    if (i >= n) return;
    if (*flag) Xb[i] = f2b(((const float*)Xraw)[i]);
    else       Xb[i] = ((const unsigned short*)Xraw)[i];
}

// ---------------- canonicalize small params to bf16 ----------------
// P layout (bf16): b1@0 g1@512 bb1@1024 b2@1536 g2@2048 bb2@2560 W3@3072 W4@3584 b4@3585
__global__ __launch_bounds__(256) void convertP_k(
    const void* b1, const void* g1, const void* bb1,
    const void* b2, const void* g2, const void* bb2,
    const void* W3, const void* W4, const void* b4,
    const int* __restrict__ flag, unsigned short* __restrict__ P)
{
    int i = blockIdx.x * 256 + threadIdx.x;
    if (i >= 3586) return;
    const void* src; int off;
    if      (i < 512)  { src = b1;  off = i; }
    else if (i < 1024) { src = g1;  off = i - 512; }
    else if (i < 1536) { src = bb1; off = i - 1024; }
    else if (i < 2048) { src = b2;  off = i - 1536; }
    else if (i < 2560) { src = g2;  off = i - 2048; }
    else if (i < 3072) { src = bb2; off = i - 2560; }
    else if (i < 3584) { src = W3;  off = i - 3072; }
    else if (i == 3584){ src = W4;  off = 0; }
    else               { src = b4;  off = 0; }
    unsigned short v;
    if (*flag) v = f2b(((const float*)src)[off]);
    else       v = ((const unsigned short*)src)[off];
    P[i] = v;
}

// ---------------- transpose W (512x512, two matrices) -> WT[n][k] bf16 ----------------
__global__ __launch_bounds__(256) void transpose_k(const void* __restrict__ W1,
                                                   const void* __restrict__ W2,
                                                   const int* __restrict__ flag,
                                                   unsigned short* __restrict__ T1,
                                                   unsigned short* __restrict__ T2) {
    __shared__ unsigned short t[32][33];
    const void*     W = blockIdx.z ? W2 : W1;
    unsigned short* T = blockIdx.z ? T2 : T1;
    const int isf = *flag;
    int tx = threadIdx.x & 31, ty = threadIdx.x >> 5;   // 32 x 8
    int n0 = blockIdx.x * 32, k0 = blockIdx.y * 32;
#pragma unroll
    for (int r = 0; r < 4; r++) {
        int k = k0 + ty + r * 8;
        unsigned short v;
        if (isf) v = f2b(((const float*)W)[k * 512 + n0 + tx]);
        else     v = ((const unsigned short*)W)[k * 512 + n0 + tx];
        t[ty + r * 8][tx] = v;
    }
    __syncthreads();
#pragma unroll
    for (int r = 0; r < 4; r++) {
        int n = n0 + ty + r * 8;
        T[n * 512 + k0 + tx] = t[tx][ty + r * 8];
    }
}

// ---------------- zero-init max/sum buffers ----------------
__global__ __launch_bounds__(256) void zero_k(float* __restrict__ p, int n) {
    int i = blockIdx.x * 256 + threadIdx.x;
    if (i < n) p[i] = 0.f;
}

// ---------------- fused GEMM (X @ W) + bias + LayerNorm -> a12 (bf16) ----------------
// Block: 32 rows x 512 cols, K=512, BK=32, 256 threads (4 waves), sel = W1/W2.
// LDS tiles are chunk-major: slot(c, r) = c*R + r holds elements [r][c*8 .. c*8+7]
// so global_load_lds (base + lane*16) stages it and ds_read_b128 reads are conflict-free.
__global__ __launch_bounds__(256) void gemm_ln_k(
    const unsigned short* __restrict__ X,     // 20000 x 512 (canonical bf16)
    const unsigned short* __restrict__ WT1,   // 512(n) x 512(k)  (pre-transposed bf16)
    const unsigned short* __restrict__ WT2,
    const unsigned short* __restrict__ bia1, const unsigned short* __restrict__ gg1, const unsigned short* __restrict__ sh1,
    const unsigned short* __restrict__ bia2, const unsigned short* __restrict__ gg2, const unsigned short* __restrict__ sh2,
    unsigned short* __restrict__ a12)         // 20000 x 1024  (a1 | a2 interleaved)
{
    __shared__ __align__(16) unsigned short Sbuf[17408]; // A: 1024 elems, B: 16384 elems; epilogue reuses as 32x520 out-tile
    __shared__ float red[32][4][2];
    unsigned short* Ab = Sbuf;          // 32 rows x 32 k, chunk-major (4 chunks x 32 rows)
    unsigned short* Bb = Sbuf + 1024;   // 512 n  x 32 k, chunk-major (4 chunks x 512 n)

    const int sel = blockIdx.y;
    const unsigned short* WT  = sel ? WT2 : WT1;
    const unsigned short* bia = sel ? bia2 : bia1;
    const unsigned short* gg  = sel ? gg2 : gg1;
    const unsigned short* sh  = sel ? sh2 : sh1;
    const int r0   = blockIdx.x * 32;
    const int tid  = threadIdx.x;
    const int lane = tid & 63;
    const int w    = tid >> 6;
    const int aq   = lane >> 4;
    const int l15  = lane & 15;

    f32x4 acc[2][8];
#pragma unroll
    for (int i = 0; i < 2; i++)
#pragma unroll
        for (int j = 0; j < 8; j++) acc[i][j] = (f32x4){0.f, 0.f, 0.f, 0.f};

    for (int k0 = 0; k0 < 512; k0 += 32) {
        if (w < 2) {  // stage A: 128 slots of 16B, waves 0-1
            int sid = w * 64 + lane;               // == c*32 + r
            int c = sid >> 5, r = sid & 31;
            const unsigned short* g = X + (r0 + r) * 512 + k0 + c * 8;
            __builtin_amdgcn_global_load_lds((const __attribute__((address_space(1))) void*)g,
                                             (__attribute__((address_space(3))) void*)(Ab + sid * 8), 16, 0, 0);
        }
#pragma unroll
        for (int u = 0; u < 8; u++) {  // stage B: 2048 slots of 16B
            int sid = (u * 4 + w) * 64 + lane;     // == c*512 + n
            int c = sid >> 9, n = sid & 511;
            const unsigned short* g = WT + n * 512 + k0 + c * 8;
            __builtin_amdgcn_global_load_lds((const __attribute__((address_space(1))) void*)g,
                                             (__attribute__((address_space(3))) void*)(Bb + sid * 8), 16, 0, 0);
        }
        __syncthreads();
        // A frags: A[m = rt*16+l15][k = aq*8+j]  -> slot aq*32 + rt*16 + l15
        short8 af0 = *(const short8*)(Ab + (aq * 32 + l15) * 8);
        short8 af1 = *(const short8*)(Ab + (aq * 32 + 16 + l15) * 8);
#pragma unroll
        for (int nt = 0; nt < 8; nt++) {
            // B frag: B[k = aq*8+j][n = w*128+nt*16+l15] -> slot aq*512 + n
            short8 bf = *(const short8*)(Bb + (aq * 512 + w * 128 + nt * 16 + l15) * 8);
            acc[0][nt] = __builtin_amdgcn_mfma_f32_16x16x32_bf16(af0, bf, acc[0][nt], 0, 0, 0);
            acc[1][nt] = __builtin_amdgcn_mfma_f32_16x16x32_bf16(af1, bf, acc[1][nt], 0, 0, 0);
        }
        __syncthreads();
    }

    // ---- epilogue: bias + LayerNorm + bf16 store ----
    float bcol[8], gcol[8], shcol[8];
#pragma unroll
    for (int nt = 0; nt < 8; nt++) {
        int col = w * 128 + nt * 16 + l15;
        bcol[nt]  = b2f(bia[col]);
        gcol[nt]  = b2f(gg[col]);
        shcol[nt] = b2f(sh[col]);
    }
#pragma unroll
    for (int rt = 0; rt < 2; rt++)
#pragma unroll
        for (int nt = 0; nt < 8; nt++)
#pragma unroll
            for (int r = 0; r < 4; r++) acc[rt][nt][r] += bcol[nt];

    // per-(wave,row) partial sums over this wave's 128 cols, then cross-wave via LDS
#pragma unroll
    for (int rt = 0; rt < 2; rt++)
#pragma unroll
        for (int r = 0; r < 4; r++) {
            float s = 0.f, q = 0.f;
#pragma unroll
            for (int nt = 0; nt < 8; nt++) { float x = acc[rt][nt][r]; s += x; q += x * x; }
#pragma unroll
            for (int off = 1; off < 16; off <<= 1) {
                s += __shfl_xor(s, off, 64);
                q += __shfl_xor(q, off, 64);
            }
            if (l15 == 0) {
                int row = rt * 16 + aq * 4 + r;
                red[row][w][0] = s;
                red[row][w][1] = q;
            }
        }
    __syncthreads();

    float mean_[2][4], rstd_[2][4];
#pragma unroll
    for (int rt = 0; rt < 2; rt++)
#pragma unroll
        for (int r = 0; r < 4; r++) {
            int row = rt * 16 + aq * 4 + r;
            float s = red[row][0][0] + red[row][1][0] + red[row][2][0] + red[row][3][0];
            float q = red[row][0][1] + red[row][1][1] + red[row][2][1] + red[row][3][1];
            float mu  = s * (1.f / 512.f);
            float var = q * (1.f / 512.f) - mu * mu;
            mean_[rt][r] = mu;
            rstd_[rt][r] = rsqrtf(var + 1e-5f);
        }

    // normalized values -> LDS out-tile (stride 520 keeps 16B alignment), then coalesced store
    unsigned short* ot = Sbuf;
#pragma unroll
    for (int rt = 0; rt < 2; rt++)
#pragma unroll
        for (int nt = 0; nt < 8; nt++)
#pragma unroll
            for (int r = 0; r < 4; r++) {
                int row = rt * 16 + aq * 4 + r;
                int col = w * 128 + nt * 16 + l15;
                float v = (acc[rt][nt][r] - mean_[rt][r]) * rstd_[rt][r] * gcol[nt] + shcol[nt];
                ot[row * 520 + col] = f2b(v);
            }
    __syncthreads();

    unsigned short* obase = a12 + (size_t)r0 * 1024 + sel * 512;
#pragma unroll
    for (int u = 0; u < 8; u++) {
        int ci  = u * 256 + tid;         // 2048 chunks of 8 bf16
        int row = ci >> 6, cc = (ci & 63) * 8;
        short8 vch = *(const short8*)(ot + row * 520 + cc);
        *(short8*)(obase + (size_t)row * 1024 + cc) = vch;
    }
}

// ---------------- per-edge: Z dot products, V = relu(+-d*w4+b4), segment max ----------------
__global__ __launch_bounds__(256) void edge_k(
    const unsigned short* __restrict__ a12,
    const int* __restrict__ eidx,            // (B, 2, E)
    const unsigned short* __restrict__ W3,   // 512 (canonical bf16, in P)
    const unsigned short* __restrict__ W4,   // 1
    const unsigned short* __restrict__ b4p,  // 1
    float* __restrict__ Vij, float* __restrict__ Vji,
    unsigned int* __restrict__ maxI, unsigned int* __restrict__ maxJ)
{
    int gw   = (blockIdx.x * 256 + threadIdx.x) >> 6;  // one wave per edge
    int lane = threadIdx.x & 63;
    if (gw >= BE) return;
    int b = gw / EE, e = gw - b * EE;
    int src = eidx[b * 2 * EE + e];
    int dst = eidx[b * 2 * EE + EE + e];
    const unsigned short* rs = a12 + (size_t)(b * NN + src) * 1024;
    const unsigned short* rd = a12 + (size_t)(b * NN + dst) * 1024;
    int o = lane * 8;
    short8 a1s = *(const short8*)(rs + o);
    short8 a2s = *(const short8*)(rs + 512 + o);
    short8 a1d = *(const short8*)(rd + o);
    short8 a2d = *(const short8*)(rd + 512 + o);
    short8 w3v = *(const short8*)(W3 + o);
    float zij = 0.f, zji = 0.f;
#pragma unroll
    for (int j = 0; j < 8; j++) {
        float wv  = b2f((unsigned short)w3v[j]);
        float x1s = b2f((unsigned short)a1s[j]);
        float x2s = b2f((unsigned short)a2s[j]);
        float x1d = b2f((unsigned short)a1d[j]);
        float x2d = b2f((unsigned short)a2d[j]);
        float pij = x1s + x2d; pij = pij > 0.f ? pij : 0.f;
        float pji = x1d + x2s; pji = pji > 0.f ? pji : 0.f;
        zij = fmaf(pij, wv, zij);
        zji = fmaf(pji, wv, zji);
    }
#pragma unroll
    for (int off = 32; off >= 1; off >>= 1) {
        zij += __shfl_xor(zij, off, 64);
        zji += __shfl_xor(zji, off, 64);
    }
    if (lane == 0) {
        float w4f = b2f(W4[0]);
        float b4f = b2f(b4p[0]);
        float d   = zij - zji;                    // b3 cancels exactly
        float vij = fmaf(d, w4f, b4f);  vij = vij > 0.f ? vij : 0.f;
        float vji = fmaf(-d, w4f, b4f); vji = vji > 0.f ? vji : 0.f;
        Vij[gw] = vij;
        Vji[gw] = vji;
        // values >= 0 -> uint-bit ordering == float ordering, 0-init is exact segment max
        atomicMax(maxI + b * NN + src, __float_as_uint(vij));
        atomicMax(maxJ + b * NN + dst, __float_as_uint(vji));
    }
}

// ---------------- softmax pass 2: e = exp(v - m[seg]); segment sums ----------------
__global__ __launch_bounds__(256) void expsum_k(
    float* __restrict__ V,                    // Vij (BE) then Vji (BE)
    const int* __restrict__ eidx,
    const float* __restrict__ maxI, const float* __restrict__ maxJ,
    float* __restrict__ sumI, float* __restrict__ sumJ)
{
    int i = blockIdx.x * 256 + threadIdx.x;
    if (i >= 2 * BE) return;
    int seg; const float* mx; float* sm;
    if (i < BE) {
        int b = i / EE, e = i - b * EE;
        seg = b * NN + eidx[b * 2 * EE + e];
        mx = maxI; sm = sumI;
    } else {
        int j = i - BE;
        int b = j / EE, e = j - b * EE;
        seg = b * NN + eidx[b * 2 * EE + EE + e];
        mx = maxJ; sm = sumJ;
    }
    float v  = V[i];
    float ex = expf(v - mx[seg]);
    V[i] = ex;
    atomicAdd(sm + seg, ex);
}

// ---------------- softmax pass 3: normalize -> bf16 or f32 out ----------------
__global__ __launch_bounds__(256) void norm_k(
    const float* __restrict__ V, const int* __restrict__ eidx,
    const float* __restrict__ sumI, const float* __restrict__ sumJ,
    const int* __restrict__ flag, void* __restrict__ out)
{
    int i = blockIdx.x * 256 + threadIdx.x;
    if (i >= 2 * BE) return;
    int seg; const float* sm;
    if (i < BE) {
        int b = i / EE, e = i - b * EE;
        seg = b * NN + eidx[b * 2 * EE + e];
        sm = sumI;
    } else {
        int j = i - BE;
        int b = j / EE, e = j - b * EE;
        seg = b * NN + eidx[b * 2 * EE + EE + e];
        sm = sumJ;
    }
    float v = V[i] / sm[seg];
    if (*flag) ((float*)out)[i] = v;
    else       ((unsigned short*)out)[i] = f2b(v);
}

extern "C" void kernel_launch(void* const* d_in, const int* in_sizes, int n_in,
                              void* d_out, int out_size, void* d_ws, size_t ws_size,
                              hipStream_t stream)
{
    (void)in_sizes; (void)n_in; (void)out_size; (void)ws_size;
    const void* X_raw = d_in[0];
    const int*  eix   = (const int*)d_in[1];
    const void* W1    = d_in[3];
    const void* b1    = d_in[4];
    const void* g1    = d_in[5];
    const void* bb1   = d_in[6];
    const void* W2    = d_in[7];
    const void* b2    = d_in[8];
    const void* g2    = d_in[9];
    const void* bb2   = d_in[10];
    const void* W3    = d_in[11];
    const void* W4    = d_in[13];
    const void* b4    = d_in[14];

    char* ws = (char*)d_ws;
    size_t off = 0;
    int* flag = (int*)(ws + off);                        off += 16;
    unsigned short* a12 = (unsigned short*)(ws + off);   off += (size_t)M_ROWS * 1024 * 2; // 40.96 MB
    unsigned short* Xb  = (unsigned short*)(ws + off);   off += (size_t)M_ROWS * 512 * 2;  // 20.48 MB
    unsigned short* T1  = (unsigned short*)(ws + off);   off += (size_t)512 * 512 * 2;
    unsigned short* T2  = (unsigned short*)(ws + off);   off += (size_t)512 * 512 * 2;
    unsigned short* P   = (unsigned short*)(ws + off);   off += 8192;
    float* Vbuf = (float*)(ws + off);                    off += (size_t)2 * BE * 4;
    float* Z    = (float*)(ws + off);                    off += (size_t)4 * BB * NN * 4;
    float* maxI = Z;
    float* maxJ = Z + BB * NN;
    float* sumI = Z + 2 * BB * NN;
    float* sumJ = Z + 3 * BB * NN;

    detect_k<<<1, 64, 0, stream>>>((const unsigned short*)X_raw, flag);
    convertX_k<<<(M_ROWS * 512 + 255) / 256, 256, 0, stream>>>(X_raw, flag, Xb, M_ROWS * 512);
    convertP_k<<<15, 256, 0, stream>>>(b1, g1, bb1, b2, g2, bb2, W3, W4, b4, flag, P);
    transpose_k<<<dim3(16, 16, 2), 256, 0, stream>>>(W1, W2, flag, T1, T2);
    zero_k<<<(4 * BB * NN + 255) / 256, 256, 0, stream>>>(Z, 4 * BB * NN);
    gemm_ln_k<<<dim3(M_ROWS / 32, 2), 256, 0, stream>>>(Xb, T1, T2,
                                                        P, P + 512, P + 1024,
                                                        P + 1536, P + 2048, P + 2560, a12);
    edge_k<<<BE / 4, 256, 0, stream>>>(a12, eix, P + 3072, P + 3584, P + 3585,
                                       Vbuf, Vbuf + BE,
                                       (unsigned int*)maxI, (unsigned int*)maxJ);
    expsum_k<<<(2 * BE + 255) / 256, 256, 0, stream>>>(Vbuf, eix, maxI, maxJ, sumI, sumJ);
    norm_k<<<(2 * BE + 255) / 256, 256, 0, stream>>>(Vbuf, eix, sumI, sumJ, flag, (unsigned short*)d_out);
}

// Round 4
// 365.137 us; speedup vs baseline: 1.1508x; 1.1508x over previous
//
#include <hip/hip_runtime.h>
#include <stdint.h>

// Problem constants (fixed by the reference setup)
#define BB 2
#define NN 10000
#define EE 100000
#define FF 512
#define HH 512
constexpr int M_ROWS = BB * NN;   // 20000 GEMM rows
constexpr int M_PAD  = 20096;     // padded to multiple of 128
constexpr int BE     = BB * EE;   // 200000 edges total

typedef __attribute__((ext_vector_type(8))) short short8;   // 8 bf16 (4 VGPRs)
typedef __attribute__((ext_vector_type(4))) float f32x4;    // MFMA accumulator

__device__ __forceinline__ float b2f(unsigned short u) {
    union { unsigned int i; float f; } v; v.i = ((unsigned int)u) << 16; return v.f;
}
__device__ __forceinline__ unsigned short f2b(float f) {   // round-to-nearest-even
    unsigned int x = __float_as_uint(f);
    x += 0x7fffu + ((x >> 16) & 1u);
    return (unsigned short)(x >> 16);
}

// ---------------- dtype detection ----------------
// flag = 1 -> inputs/outputs are float32; flag = 0 -> bfloat16.
__global__ void detect_k(const unsigned short* __restrict__ x, int* __restrict__ flag) {
    if (threadIdx.x == 0 && blockIdx.x == 0) {
        int good = 0;
        for (int i = 0; i < 128; i++) {
            unsigned short u = x[2 * i];
            int e = (u >> 7) & 0xFF;
            if (e >= 100 && e <= 140) good++;
        }
        *flag = (good < 96) ? 1 : 0;
    }
}

// ---------------- canonicalize X to bf16 ----------------
__global__ __launch_bounds__(256) void convertX_k(const void* __restrict__ Xraw,
                                                  const int* __restrict__ flag,
                                                  unsigned short* __restrict__ Xb, int n) {
    int i = blockIdx.x * 256 + threadIdx.x;
    if (i >= n) return;
    if (*flag) Xb[i] = f2b(((const float*)Xraw)[i]);
    else       Xb[i] = ((const unsigned short*)Xraw)[i];
}

// ---------------- canonicalize small params to bf16 ----------------
// P layout (bf16): b1@0 g1@512 bb1@1024 b2@1536 g2@2048 bb2@2560 W3@3072 W4@3584 b4@3585
__global__ __launch_bounds__(256) void convertP_k(
    const void* b1, const void* g1, const void* bb1,
    const void* b2, const void* g2, const void* bb2,
    const void* W3, const void* W4, const void* b4,
    const int* __restrict__ flag, unsigned short* __restrict__ P)
{
    int i = blockIdx.x * 256 + threadIdx.x;
    if (i >= 3586) return;
    const void* src; int off;
    if      (i < 512)  { src = b1;  off = i; }
    else if (i < 1024) { src = g1;  off = i - 512; }
    else if (i < 1536) { src = bb1; off = i - 1024; }
    else if (i < 2048) { src = b2;  off = i - 1536; }
    else if (i < 2560) { src = g2;  off = i - 2048; }
    else if (i < 3072) { src = bb2; off = i - 2560; }
    else if (i < 3584) { src = W3;  off = i - 3072; }
    else if (i == 3584){ src = W4;  off = 0; }
    else               { src = b4;  off = 0; }
    unsigned short v;
    if (*flag) v = f2b(((const float*)src)[off]);
    else       v = ((const unsigned short*)src)[off];
    P[i] = v;
}

// ---------------- transpose W (512x512, two matrices) -> WT[n][k] bf16 ----------------
__global__ __launch_bounds__(256) void transpose_k(const void* __restrict__ W1,
                                                   const void* __restrict__ W2,
                                                   const int* __restrict__ flag,
                                                   unsigned short* __restrict__ T1,
                                                   unsigned short* __restrict__ T2) {
    __shared__ unsigned short t[32][33];
    const void*     W = blockIdx.z ? W2 : W1;
    unsigned short* T = blockIdx.z ? T2 : T1;
    const int isf = *flag;
    int tx = threadIdx.x & 31, ty = threadIdx.x >> 5;   // 32 x 8
    int n0 = blockIdx.x * 32, k0 = blockIdx.y * 32;
#pragma unroll
    for (int r = 0; r < 4; r++) {
        int k = k0 + ty + r * 8;
        unsigned short v;
        if (isf) v = f2b(((const float*)W)[k * 512 + n0 + tx]);
        else     v = ((const unsigned short*)W)[k * 512 + n0 + tx];
        t[ty + r * 8][tx] = v;
    }
    __syncthreads();
#pragma unroll
    for (int r = 0; r < 4; r++) {
        int n = n0 + ty + r * 8;
        T[n * 512 + k0 + tx] = t[tx][ty + r * 8];
    }
}

// ---------------- zero-init max/sum buffers ----------------
__global__ __launch_bounds__(256) void zero_k(float* __restrict__ p, int n) {
    int i = blockIdx.x * 256 + threadIdx.x;
    if (i < n) p[i] = 0.f;
}

// ---------------- fused GEMM (X @ W) + bias + LayerNorm -> a12 (bf16) ----------------
// BM=128, BN=512 (full row -> fused LN), BK=32, 512 threads (8 waves = 2 mg x 4 ng),
// double-buffered LDS with ONE barrier per k-iter: issue next-tile global_load_lds,
// then compute current tile; barrier covers both "B written" and "A-readers done".
// LDS chunk-major layout: slot(c,r) = c*R + r holds elems [r][c*8..c*8+7] so
// global_load_lds (wave-uniform base + lane*16) stages it and ds_read_b128 works.
__global__ __launch_bounds__(512, 2) void gemm_ln2_k(
    const unsigned short* __restrict__ X,     // M_PAD x 512 (canonical bf16)
    const unsigned short* __restrict__ WT1,   // 512(n) x 512(k)  (pre-transposed bf16)
    const unsigned short* __restrict__ WT2,
    const unsigned short* __restrict__ bia1, const unsigned short* __restrict__ gg1, const unsigned short* __restrict__ sh1,
    const unsigned short* __restrict__ bia2, const unsigned short* __restrict__ gg2, const unsigned short* __restrict__ sh2,
    unsigned short* __restrict__ a12)         // 20000 x 1024  (a1 | a2 interleaved)
{
    __shared__ __align__(16) unsigned short S[49152];  // 96 KB: Ab0,Ab1 (4096 ea), Bb0,Bb1 (16384 ea); epilogue reuses as 64x520 tile
    __shared__ float red[128][4][2];

    const int sel = blockIdx.y;
    const unsigned short* WT  = sel ? WT2 : WT1;
    const unsigned short* bia = sel ? bia2 : bia1;
    const unsigned short* gg  = sel ? gg2 : gg1;
    const unsigned short* sh  = sel ? sh2 : sh1;
    const int r0   = blockIdx.x * 128;
    const int tid  = threadIdx.x;
    const int lane = tid & 63;
    const int w    = tid >> 6;      // 0..7
    const int mg   = w >> 2;        // 0..1  (64-row group)
    const int ng   = w & 3;         // 0..3  (128-col group)
    const int aq   = lane >> 4;     // 0..3
    const int l15  = lane & 15;

    f32x4 acc[4][8];
#pragma unroll
    for (int i = 0; i < 4; i++)
#pragma unroll
        for (int j = 0; j < 8; j++) acc[i][j] = (f32x4){0.f, 0.f, 0.f, 0.f};

    // A staging: 512 slots (c*128 + r), one per thread
    const int a_r = tid & 127;
    const unsigned short* a_g0 = X + (size_t)(r0 + a_r) * 512 + (tid >> 7) * 8;

    // ---- prologue: stage k-tile 0 into buffer 0 ----
    {
        __builtin_amdgcn_global_load_lds((const __attribute__((address_space(1))) void*)a_g0,
                                         (__attribute__((address_space(3))) void*)(S + tid * 8), 16, 0, 0);
#pragma unroll
        for (int u = 0; u < 4; u++) {
            int slot = u * 512 + tid;           // c*512 + n
            int c = slot >> 9, n = slot & 511;
            const unsigned short* g = WT + n * 512 + c * 8;
            __builtin_amdgcn_global_load_lds((const __attribute__((address_space(1))) void*)g,
                                             (__attribute__((address_space(3))) void*)(S + 8192 + slot * 8), 16, 0, 0);
        }
    }

    for (int it = 0; it < 16; ++it) {
        const int boff  = (it & 1) ? 4096 : 0;       // current A buffer offset (elems)
        const int boffB = (it & 1) ? 16384 : 0;      // current B buffer offset (elems)
        unsigned short* Ac = S + boff;
        unsigned short* Bc = S + 8192 + boffB;
        __syncthreads();   // current buffer staged; other buffer's readers (prev iter) done
        if (it + 1 < 16) {
            const int k0 = (it + 1) * 32;
            unsigned short* An = S + (boff ^ 4096);
            unsigned short* Bn = S + 8192 + (boffB ^ 16384);
            __builtin_amdgcn_global_load_lds((const __attribute__((address_space(1))) void*)(a_g0 + k0),
                                             (__attribute__((address_space(3))) void*)(An + tid * 8), 16, 0, 0);
#pragma unroll
            for (int u = 0; u < 4; u++) {
                int slot = u * 512 + tid;
                int c = slot >> 9, n = slot & 511;
                const unsigned short* g = WT + n * 512 + k0 + c * 8;
                __builtin_amdgcn_global_load_lds((const __attribute__((address_space(1))) void*)g,
                                                 (__attribute__((address_space(3))) void*)(Bn + slot * 8), 16, 0, 0);
            }
        }
        // A frags: A[m = mg*64+mt*16+l15][k = aq*8+j] -> slot aq*128 + m
        short8 af[4];
#pragma unroll
        for (int mt = 0; mt < 4; mt++)
            af[mt] = *(const short8*)(Ac + (aq * 128 + mg * 64 + mt * 16 + l15) * 8);
#pragma unroll
        for (int nt = 0; nt < 8; nt++) {
            // B frag: B[k = aq*8+j][n = ng*128+nt*16+l15] -> slot aq*512 + n
            short8 bf = *(const short8*)(Bc + (aq * 512 + ng * 128 + nt * 16 + l15) * 8);
#pragma unroll
            for (int mt = 0; mt < 4; mt++)
                acc[mt][nt] = __builtin_amdgcn_mfma_f32_16x16x32_bf16(af[mt], bf, acc[mt][nt], 0, 0, 0);
        }
    }

    // ---- epilogue: bias + LayerNorm + bf16 store ----
    float bcol[8], gcol[8], shcol[8];
#pragma unroll
    for (int nt = 0; nt < 8; nt++) {
        int col = ng * 128 + nt * 16 + l15;
        bcol[nt]  = b2f(bia[col]);
        gcol[nt]  = b2f(gg[col]);
        shcol[nt] = b2f(sh[col]);
    }
#pragma unroll
    for (int mt = 0; mt < 4; mt++)
#pragma unroll
        for (int nt = 0; nt < 8; nt++)
#pragma unroll
            for (int r = 0; r < 4; r++) acc[mt][nt][r] += bcol[nt];

    // per-(wave,row) partials over this wave's 128 cols, then cross-wave via LDS
#pragma unroll
    for (int mt = 0; mt < 4; mt++)
#pragma unroll
        for (int r = 0; r < 4; r++) {
            float s = 0.f, q = 0.f;
#pragma unroll
            for (int nt = 0; nt < 8; nt++) { float x = acc[mt][nt][r]; s += x; q += x * x; }
#pragma unroll
            for (int off = 1; off < 16; off <<= 1) {
                s += __shfl_xor(s, off, 64);
                q += __shfl_xor(q, off, 64);
            }
            if (l15 == 0) {
                int row = mg * 64 + mt * 16 + aq * 4 + r;
                red[row][ng][0] = s;
                red[row][ng][1] = q;
            }
        }
    __syncthreads();

    float mean_[4][4], rstd_[4][4];
#pragma unroll
    for (int mt = 0; mt < 4; mt++)
#pragma unroll
        for (int r = 0; r < 4; r++) {
            int row = mg * 64 + mt * 16 + aq * 4 + r;
            float s = red[row][0][0] + red[row][1][0] + red[row][2][0] + red[row][3][0];
            float q = red[row][0][1] + red[row][1][1] + red[row][2][1] + red[row][3][1];
            float mu  = s * (1.f / 512.f);
            float var = q * (1.f / 512.f) - mu * mu;
            mean_[mt][r] = mu;
            rstd_[mt][r] = rsqrtf(var + 1e-5f);
        }

    // two 64-row halves through LDS (stride 520 keeps 16B alignment), coalesced store
    unsigned short* ot = S;
    unsigned short* obase = a12 + sel * 512;
#pragma unroll 1
    for (int h = 0; h < 2; ++h) {
        __syncthreads();
        if (mg == h) {
#pragma unroll
            for (int mt = 0; mt < 4; mt++)
#pragma unroll
                for (int nt = 0; nt < 8; nt++)
#pragma unroll
                    for (int r = 0; r < 4; r++) {
                        int row = mt * 16 + aq * 4 + r;
                        int col = ng * 128 + nt * 16 + l15;
                        float v = (acc[mt][nt][r] - mean_[mt][r]) * rstd_[mt][r] * gcol[nt] + shcol[nt];
                        ot[row * 520 + col] = f2b(v);
                    }
        }
        __syncthreads();
#pragma unroll
        for (int u = 0; u < 8; u++) {
            int ci  = u * 512 + tid;          // 4096 chunks of 8 bf16
            int row = ci >> 6, cc = (ci & 63) * 8;
            int gr  = r0 + h * 64 + row;
            if (gr < M_ROWS) {
                short8 vch = *(const short8*)(ot + row * 520 + cc);
                *(short8*)(obase + (size_t)gr * 1024 + cc) = vch;
            }
        }
    }
}

// ---------------- per-edge: Z dot products, V = relu(+-d*w4+b4), segment max ----------------
__global__ __launch_bounds__(256) void edge_k(
    const unsigned short* __restrict__ a12,
    const int* __restrict__ eidx,            // (B, 2, E)
    const unsigned short* __restrict__ W3,   // 512 (canonical bf16, in P)
    const unsigned short* __restrict__ W4,   // 1
    const unsigned short* __restrict__ b4p,  // 1
    float* __restrict__ Vij, float* __restrict__ Vji,
    unsigned int* __restrict__ maxI, unsigned int* __restrict__ maxJ)
{
    int gw   = (blockIdx.x * 256 + threadIdx.x) >> 6;  // one wave per edge
    int lane = threadIdx.x & 63;
    if (gw >= BE) return;
    int b = gw / EE, e = gw - b * EE;
    int src = eidx[b * 2 * EE + e];
    int dst = eidx[b * 2 * EE + EE + e];
    const unsigned short* rs = a12 + (size_t)(b * NN + src) * 1024;
    const unsigned short* rd = a12 + (size_t)(b * NN + dst) * 1024;
    int o = lane * 8;
    short8 a1s = *(const short8*)(rs + o);
    short8 a2s = *(const short8*)(rs + 512 + o);
    short8 a1d = *(const short8*)(rd + o);
    short8 a2d = *(const short8*)(rd + 512 + o);
    short8 w3v = *(const short8*)(W3 + o);
    float zij = 0.f, zji = 0.f;
#pragma unroll
    for (int j = 0; j < 8; j++) {
        float wv  = b2f((unsigned short)w3v[j]);
        float x1s = b2f((unsigned short)a1s[j]);
        float x2s = b2f((unsigned short)a2s[j]);
        float x1d = b2f((unsigned short)a1d[j]);
        float x2d = b2f((unsigned short)a2d[j]);
        float pij = x1s + x2d; pij = pij > 0.f ? pij : 0.f;
        float pji = x1d + x2s; pji = pji > 0.f ? pji : 0.f;
        zij = fmaf(pij, wv, zij);
        zji = fmaf(pji, wv, zji);
    }
#pragma unroll
    for (int off = 32; off >= 1; off >>= 1) {
        zij += __shfl_xor(zij, off, 64);
        zji += __shfl_xor(zji, off, 64);
    }
    if (lane == 0) {
        float w4f = b2f(W4[0]);
        float b4f = b2f(b4p[0]);
        float d   = zij - zji;                    // b3 cancels exactly
        float vij = fmaf(d, w4f, b4f);  vij = vij > 0.f ? vij : 0.f;
        float vji = fmaf(-d, w4f, b4f); vji = vji > 0.f ? vji : 0.f;
        Vij[gw] = vij;
        Vji[gw] = vji;
        // values >= 0 -> uint-bit ordering == float ordering, 0-init is exact segment max
        atomicMax(maxI + b * NN + src, __float_as_uint(vij));
        atomicMax(maxJ + b * NN + dst, __float_as_uint(vji));
    }
}

// ---------------- softmax pass 2: e = exp(v - m[seg]); segment sums ----------------
__global__ __launch_bounds__(256) void expsum_k(
    float* __restrict__ V,                    // Vij (BE) then Vji (BE)
    const int* __restrict__ eidx,
    const float* __restrict__ maxI, const float* __restrict__ maxJ,
    float* __restrict__ sumI, float* __restrict__ sumJ)
{
    int i = blockIdx.x * 256 + threadIdx.x;
    if (i >= 2 * BE) return;
    int seg; const float* mx; float* sm;
    if (i < BE) {
        int b = i / EE, e = i - b * EE;
        seg = b * NN + eidx[b * 2 * EE + e];
        mx = maxI; sm = sumI;
    } else {
        int j = i - BE;
        int b = j / EE, e = j - b * EE;
        seg = b * NN + eidx[b * 2 * EE + EE + e];
        mx = maxJ; sm = sumJ;
    }
    float v  = V[i];
    float ex = expf(v - mx[seg]);
    V[i] = ex;
    atomicAdd(sm + seg, ex);
}

// ---------------- softmax pass 3: normalize -> bf16 or f32 out ----------------
__global__ __launch_bounds__(256) void norm_k(
    const float* __restrict__ V, const int* __restrict__ eidx,
    const float* __restrict__ sumI, const float* __restrict__ sumJ,
    const int* __restrict__ flag, void* __restrict__ out)
{
    int i = blockIdx.x * 256 + threadIdx.x;
    if (i >= 2 * BE) return;
    int seg; const float* sm;
    if (i < BE) {
        int b = i / EE, e = i - b * EE;
        seg = b * NN + eidx[b * 2 * EE + e];
        sm = sumI;
    } else {
        int j = i - BE;
        int b = j / EE, e = j - b * EE;
        seg = b * NN + eidx[b * 2 * EE + EE + e];
        sm = sumJ;
    }
    float v = V[i] / sm[seg];
    if (*flag) ((float*)out)[i] = v;
    else       ((unsigned short*)out)[i] = f2b(v);
}

extern "C" void kernel_launch(void* const* d_in, const int* in_sizes, int n_in,
                              void* d_out, int out_size, void* d_ws, size_t ws_size,
                              hipStream_t stream)
{
    (void)in_sizes; (void)n_in; (void)out_size; (void)ws_size;
    const void* X_raw = d_in[0];
    const int*  eix   = (const int*)d_in[1];
    const void* W1    = d_in[3];
    const void* b1    = d_in[4];
    const void* g1    = d_in[5];
    const void* bb1   = d_in[6];
    const void* W2    = d_in[7];
    const void* b2    = d_in[8];
    const void* g2    = d_in[9];
    const void* bb2   = d_in[10];
    const void* W3    = d_in[11];
    const void* W4    = d_in[13];
    const void* b4    = d_in[14];

    char* ws = (char*)d_ws;
    size_t off = 0;
    int* flag = (int*)(ws + off);                        off += 16;
    unsigned short* a12 = (unsigned short*)(ws + off);   off += (size_t)M_ROWS * 1024 * 2; // 40.96 MB
    unsigned short* Xb  = (unsigned short*)(ws + off);   off += (size_t)M_PAD * 512 * 2;   // 20.6 MB (padded)
    unsigned short* T1  = (unsigned short*)(ws + off);   off += (size_t)512 * 512 * 2;
    unsigned short* T2  = (unsigned short*)(ws + off);   off += (size_t)512 * 512 * 2;
    unsigned short* P   = (unsigned short*)(ws + off);   off += 8192;
    float* Vbuf = (float*)(ws + off);                    off += (size_t)2 * BE * 4;
    float* Z    = (float*)(ws + off);                    off += (size_t)4 * BB * NN * 4;
    float* maxI = Z;
    float* maxJ = Z + BB * NN;
    float* sumI = Z + 2 * BB * NN;
    float* sumJ = Z + 3 * BB * NN;

    detect_k<<<1, 64, 0, stream>>>((const unsigned short*)X_raw, flag);
    convertX_k<<<(M_ROWS * 512 + 255) / 256, 256, 0, stream>>>(X_raw, flag, Xb, M_ROWS * 512);
    convertP_k<<<15, 256, 0, stream>>>(b1, g1, bb1, b2, g2, bb2, W3, W4, b4, flag, P);
    transpose_k<<<dim3(16, 16, 2), 256, 0, stream>>>(W1, W2, flag, T1, T2);
    zero_k<<<(4 * BB * NN + 255) / 256, 256, 0, stream>>>(Z, 4 * BB * NN);
    gemm_ln2_k<<<dim3(M_PAD / 128, 2), 512, 0, stream>>>(Xb, T1, T2,
                                                         P, P + 512, P + 1024,
                                                         P + 1536, P + 2048, P + 2560, a12);
    edge_k<<<BE / 4, 256, 0, stream>>>(a12, eix, P + 3072, P + 3584, P + 3585,
                                       Vbuf, Vbuf + BE,
                                       (unsigned int*)maxI, (unsigned int*)maxJ);
    expsum_k<<<(2 * BE + 255) / 256, 256, 0, stream>>>(Vbuf, eix, maxI, maxJ, sumI, sumJ);
    norm_k<<<(2 * BE + 255) / 256, 256, 0, stream>>>(Vbuf, eix, sumI, sumJ, flag, (unsigned short*)d_out);
}

// Round 5
// 343.687 us; speedup vs baseline: 1.2226x; 1.0624x over previous
//
#include <hip/hip_runtime.h>
#include <stdint.h>

// Problem constants (fixed by the reference setup)
#define BB 2
#define NN 10000
#define EE 100000
#define FF 512
#define HH 512
constexpr int M_ROWS = BB * NN;   // 20000 GEMM rows
constexpr int M_PAD  = 20096;     // padded to multiple of 128
constexpr int BE     = BB * EE;   // 200000 edges total

typedef __attribute__((ext_vector_type(8))) short short8;   // 8 bf16 (4 VGPRs)
typedef __attribute__((ext_vector_type(4))) float f32x4;    // MFMA accumulator

__device__ __forceinline__ float b2f(unsigned short u) {
    union { unsigned int i; float f; } v; v.i = ((unsigned int)u) << 16; return v.f;
}
__device__ __forceinline__ unsigned short f2b(float f) {   // round-to-nearest-even
    unsigned int x = __float_as_uint(f);
    x += 0x7fffu + ((x >> 16) & 1u);
    return (unsigned short)(x >> 16);
}

// ---------------- dtype detection ----------------
// flag = 1 -> inputs/outputs are float32; flag = 0 -> bfloat16.
__global__ void detect_k(const unsigned short* __restrict__ x, int* __restrict__ flag) {
    if (threadIdx.x == 0 && blockIdx.x == 0) {
        int good = 0;
        for (int i = 0; i < 128; i++) {
            unsigned short u = x[2 * i];
            int e = (u >> 7) & 0xFF;
            if (e >= 100 && e <= 140) good++;
        }
        *flag = (good < 96) ? 1 : 0;
    }
}

// ---------------- canonicalize X to bf16 ----------------
__global__ __launch_bounds__(256) void convertX_k(const void* __restrict__ Xraw,
                                                  const int* __restrict__ flag,
                                                  unsigned short* __restrict__ Xb, int n) {
    int i = blockIdx.x * 256 + threadIdx.x;
    if (i >= n) return;
    if (*flag) Xb[i] = f2b(((const float*)Xraw)[i]);
    else       Xb[i] = ((const unsigned short*)Xraw)[i];
}

// ---------------- canonicalize small params to bf16 ----------------
// P layout (bf16): b1@0 g1@512 bb1@1024 b2@1536 g2@2048 bb2@2560 W3@3072 W4@3584 b4@3585
__global__ __launch_bounds__(256) void convertP_k(
    const void* b1, const void* g1, const void* bb1,
    const void* b2, const void* g2, const void* bb2,
    const void* W3, const void* W4, const void* b4,
    const int* __restrict__ flag, unsigned short* __restrict__ P)
{
    int i = blockIdx.x * 256 + threadIdx.x;
    if (i >= 3586) return;
    const void* src; int off;
    if      (i < 512)  { src = b1;  off = i; }
    else if (i < 1024) { src = g1;  off = i - 512; }
    else if (i < 1536) { src = bb1; off = i - 1024; }
    else if (i < 2048) { src = b2;  off = i - 1536; }
    else if (i < 2560) { src = g2;  off = i - 2048; }
    else if (i < 3072) { src = bb2; off = i - 2560; }
    else if (i < 3584) { src = W3;  off = i - 3072; }
    else if (i == 3584){ src = W4;  off = 0; }
    else               { src = b4;  off = 0; }
    unsigned short v;
    if (*flag) v = f2b(((const float*)src)[off]);
    else       v = ((const unsigned short*)src)[off];
    P[i] = v;
}

// ---------------- transpose W (512x512, two matrices) -> WT[n][k] bf16 ----------------
__global__ __launch_bounds__(256) void transpose_k(const void* __restrict__ W1,
                                                   const void* __restrict__ W2,
                                                   const int* __restrict__ flag,
                                                   unsigned short* __restrict__ T1,
                                                   unsigned short* __restrict__ T2) {
    __shared__ unsigned short t[32][33];
    const void*     W = blockIdx.z ? W2 : W1;
    unsigned short* T = blockIdx.z ? T2 : T1;
    const int isf = *flag;
    int tx = threadIdx.x & 31, ty = threadIdx.x >> 5;   // 32 x 8
    int n0 = blockIdx.x * 32, k0 = blockIdx.y * 32;
#pragma unroll
    for (int r = 0; r < 4; r++) {
        int k = k0 + ty + r * 8;
        unsigned short v;
        if (isf) v = f2b(((const float*)W)[k * 512 + n0 + tx]);
        else     v = ((const unsigned short*)W)[k * 512 + n0 + tx];
        t[ty + r * 8][tx] = v;
    }
    __syncthreads();
#pragma unroll
    for (int r = 0; r < 4; r++) {
        int n = n0 + ty + r * 8;
        T[n * 512 + k0 + tx] = t[tx][ty + r * 8];
    }
}

// ---------------- zero-init max/sum buffers ----------------
__global__ __launch_bounds__(256) void zero_k(float* __restrict__ p, int n) {
    int i = blockIdx.x * 256 + threadIdx.x;
    if (i < n) p[i] = 0.f;
}

// ---------------- fused GEMM (X @ W) + bias + LayerNorm -> a12 (bf16) ----------------
// BM=128, BN=512 (full row -> fused LN), BK=32, 512 threads (8 waves = 2 mg x 4 ng),
// double-buffered LDS, one barrier per k-iter.
// Staging layout (row-major + XOR swizzle): slot sid = r*4 + kc; physical chunk kc of
// row r holds GLOBAL k-chunk (kc ^ ((r>>1)&3)). Lanes advance along k -> 64 B
// contiguous per row, 16 rows per wave = perfectly coalesced (16 lines / KB).
// Fragment reads hit super-bank aq ^ ((row>>1)&3) -> 2-way only (free).
__global__ __launch_bounds__(512, 2) void gemm_ln2_k(
    const unsigned short* __restrict__ X,     // M_PAD x 512 (canonical bf16)
    const unsigned short* __restrict__ WT1,   // 512(n) x 512(k)  (pre-transposed bf16)
    const unsigned short* __restrict__ WT2,
    const unsigned short* __restrict__ bia1, const unsigned short* __restrict__ gg1, const unsigned short* __restrict__ sh1,
    const unsigned short* __restrict__ bia2, const unsigned short* __restrict__ gg2, const unsigned short* __restrict__ sh2,
    unsigned short* __restrict__ a12)         // 20000 x 1024  (a1 | a2 interleaved)
{
    __shared__ __align__(16) unsigned short S[49152];  // 96 KB: Ab0,Ab1 (4096 ea), Bb0,Bb1 (16384 ea); epilogue reuses as 64x520 tile
    __shared__ float red[128][4][2];

    const int sel = blockIdx.y;
    const unsigned short* WT  = sel ? WT2 : WT1;
    const unsigned short* bia = sel ? bia2 : bia1;
    const unsigned short* gg  = sel ? gg2 : gg1;
    const unsigned short* sh  = sel ? sh2 : sh1;
    const int r0   = blockIdx.x * 128;
    const int tid  = threadIdx.x;
    const int lane = tid & 63;
    const int w    = tid >> 6;      // 0..7
    const int mg   = w >> 2;        // 0..1  (64-row group)
    const int ng   = w & 3;         // 0..3  (128-col group)
    const int aq   = lane >> 4;     // 0..3
    const int l15  = lane & 15;

    f32x4 acc[4][8];
#pragma unroll
    for (int i = 0; i < 4; i++)
#pragma unroll
        for (int j = 0; j < 8; j++) acc[i][j] = (f32x4){0.f, 0.f, 0.f, 0.f};

    // A staging address: r = tid>>2, kc = tid&3, swizzled chunk kc^((r>>1)&3)
    const int a_rr  = tid >> 2;
    const int a_kc  = (tid & 3) ^ ((a_rr >> 1) & 3);
    const unsigned short* a_g0 = X + (size_t)(r0 + a_rr) * 512 + a_kc * 8;

    // B staging addresses (4 slots per thread): sid = u*512+tid, n = sid>>2, kc = sid&3
    // n = (u*512+tid)>>2 = u*128 + (tid>>2); kc = tid&3 (u*512 doesn't touch low bits)
    const int b_n0  = tid >> 2;
    const int b_kc  = (tid & 3);

    // ---- prologue: stage k-tile 0 into buffer 0 ----
    {
        __builtin_amdgcn_global_load_lds((const __attribute__((address_space(1))) void*)a_g0,
                                         (__attribute__((address_space(3))) void*)(S + tid * 8), 16, 0, 0);
#pragma unroll
        for (int u = 0; u < 4; u++) {
            int n   = u * 128 + b_n0;
            int kcs = b_kc ^ ((n >> 1) & 3);
            const unsigned short* g = WT + n * 512 + kcs * 8;
            __builtin_amdgcn_global_load_lds((const __attribute__((address_space(1))) void*)g,
                                             (__attribute__((address_space(3))) void*)(S + 8192 + (u * 512 + tid) * 8), 16, 0, 0);
        }
    }

    for (int it = 0; it < 16; ++it) {
        const int boff  = (it & 1) ? 4096 : 0;       // current A buffer offset (elems)
        const int boffB = (it & 1) ? 16384 : 0;      // current B buffer offset (elems)
        unsigned short* Ac = S + boff;
        unsigned short* Bc = S + 8192 + boffB;
        __syncthreads();   // current buffer staged; other buffer's readers (prev iter) done
        if (it + 1 < 16) {
            const int k0 = (it + 1) * 32;
            unsigned short* An = S + (boff ^ 4096);
            unsigned short* Bn = S + 8192 + (boffB ^ 16384);
            __builtin_amdgcn_global_load_lds((const __attribute__((address_space(1))) void*)(a_g0 + k0),
                                             (__attribute__((address_space(3))) void*)(An + tid * 8), 16, 0, 0);
#pragma unroll
            for (int u = 0; u < 4; u++) {
                int n   = u * 128 + b_n0;
                int kcs = b_kc ^ ((n >> 1) & 3);
                const unsigned short* g = WT + n * 512 + k0 + kcs * 8;
                __builtin_amdgcn_global_load_lds((const __attribute__((address_space(1))) void*)g,
                                                 (__attribute__((address_space(3))) void*)(Bn + (u * 512 + tid) * 8), 16, 0, 0);
            }
        }
        // A frags: A[m][k=aq*8+j] -> row m (32 elems), swizzled chunk aq^((m>>1)&3)
        short8 af[4];
#pragma unroll
        for (int mt = 0; mt < 4; mt++) {
            int m = mg * 64 + mt * 16 + l15;
            af[mt] = *(const short8*)(Ac + m * 32 + (aq ^ ((m >> 1) & 3)) * 8);
        }
#pragma unroll
        for (int nt = 0; nt < 8; nt++) {
            int n = ng * 128 + nt * 16 + l15;
            short8 bf = *(const short8*)(Bc + n * 32 + (aq ^ ((n >> 1) & 3)) * 8);
#pragma unroll
            for (int mt = 0; mt < 4; mt++)
                acc[mt][nt] = __builtin_amdgcn_mfma_f32_16x16x32_bf16(af[mt], bf, acc[mt][nt], 0, 0, 0);
        }
    }

    // ---- epilogue: bias + LayerNorm + bf16 store ----
    float bcol[8], gcol[8], shcol[8];
#pragma unroll
    for (int nt = 0; nt < 8; nt++) {
        int col = ng * 128 + nt * 16 + l15;
        bcol[nt]  = b2f(bia[col]);
        gcol[nt]  = b2f(gg[col]);
        shcol[nt] = b2f(sh[col]);
    }
#pragma unroll
    for (int mt = 0; mt < 4; mt++)
#pragma unroll
        for (int nt = 0; nt < 8; nt++)
#pragma unroll
            for (int r = 0; r < 4; r++) acc[mt][nt][r] += bcol[nt];

    // per-(wave,row) partials over this wave's 128 cols, then cross-wave via LDS
#pragma unroll
    for (int mt = 0; mt < 4; mt++)
#pragma unroll
        for (int r = 0; r < 4; r++) {
            float s = 0.f, q = 0.f;
#pragma unroll
            for (int nt = 0; nt < 8; nt++) { float x = acc[mt][nt][r]; s += x; q += x * x; }
#pragma unroll
            for (int off = 1; off < 16; off <<= 1) {
                s += __shfl_xor(s, off, 64);
                q += __shfl_xor(q, off, 64);
            }
            if (l15 == 0) {
                int row = mg * 64 + mt * 16 + aq * 4 + r;
                red[row][ng][0] = s;
                red[row][ng][1] = q;
            }
        }
    __syncthreads();

    float mean_[4][4], rstd_[4][4];
#pragma unroll
    for (int mt = 0; mt < 4; mt++)
#pragma unroll
        for (int r = 0; r < 4; r++) {
            int row = mg * 64 + mt * 16 + aq * 4 + r;
            float s = red[row][0][0] + red[row][1][0] + red[row][2][0] + red[row][3][0];
            float q = red[row][0][1] + red[row][1][1] + red[row][2][1] + red[row][3][1];
            float mu  = s * (1.f / 512.f);
            float var = q * (1.f / 512.f) - mu * mu;
            mean_[mt][r] = mu;
            rstd_[mt][r] = rsqrtf(var + 1e-5f);
        }

    // two 64-row halves through LDS (stride 520 keeps 16B alignment), coalesced store
    unsigned short* ot = S;
    unsigned short* obase = a12 + sel * 512;
#pragma unroll 1
    for (int h = 0; h < 2; ++h) {
        __syncthreads();
        if (mg == h) {
#pragma unroll
            for (int mt = 0; mt < 4; mt++)
#pragma unroll
                for (int nt = 0; nt < 8; nt++)
#pragma unroll
                    for (int r = 0; r < 4; r++) {
                        int row = mt * 16 + aq * 4 + r;
                        int col = ng * 128 + nt * 16 + l15;
                        float v = (acc[mt][nt][r] - mean_[mt][r]) * rstd_[mt][r] * gcol[nt] + shcol[nt];
                        ot[row * 520 + col] = f2b(v);
                    }
        }
        __syncthreads();
#pragma unroll
        for (int u = 0; u < 8; u++) {
            int ci  = u * 512 + tid;          // 4096 chunks of 8 bf16
            int row = ci >> 6, cc = (ci & 63) * 8;
            int gr  = r0 + h * 64 + row;
            if (gr < M_ROWS) {
                short8 vch = *(const short8*)(ot + row * 520 + cc);
                *(short8*)(obase + (size_t)gr * 1024 + cc) = vch;
            }
        }
    }
}

// ---------------- per-edge: Z dot products, V = relu(+-d*w4+b4), segment max ----------------
__global__ __launch_bounds__(256) void edge_k(
    const unsigned short* __restrict__ a12,
    const int* __restrict__ eidx,            // (B, 2, E)
    const unsigned short* __restrict__ W3,   // 512 (canonical bf16, in P)
    const unsigned short* __restrict__ W4,   // 1
    const unsigned short* __restrict__ b4p,  // 1
    float* __restrict__ Vij, float* __restrict__ Vji,
    unsigned int* __restrict__ maxI, unsigned int* __restrict__ maxJ)
{
    int gw   = (blockIdx.x * 256 + threadIdx.x) >> 6;  // one wave per edge
    int lane = threadIdx.x & 63;
    if (gw >= BE) return;
    int b = gw / EE, e = gw - b * EE;
    int src = eidx[b * 2 * EE + e];
    int dst = eidx[b * 2 * EE + EE + e];
    const unsigned short* rs = a12 + (size_t)(b * NN + src) * 1024;
    const unsigned short* rd = a12 + (size_t)(b * NN + dst) * 1024;
    int o = lane * 8;
    short8 a1s = *(const short8*)(rs + o);
    short8 a2s = *(const short8*)(rs + 512 + o);
    short8 a1d = *(const short8*)(rd + o);
    short8 a2d = *(const short8*)(rd + 512 + o);
    short8 w3v = *(const short8*)(W3 + o);
    float zij = 0.f, zji = 0.f;
#pragma unroll
    for (int j = 0; j < 8; j++) {
        float wv  = b2f((unsigned short)w3v[j]);
        float x1s = b2f((unsigned short)a1s[j]);
        float x2s = b2f((unsigned short)a2s[j]);
        float x1d = b2f((unsigned short)a1d[j]);
        float x2d = b2f((unsigned short)a2d[j]);
        float pij = x1s + x2d; pij = pij > 0.f ? pij : 0.f;
        float pji = x1d + x2s; pji = pji > 0.f ? pji : 0.f;
        zij = fmaf(pij, wv, zij);
        zji = fmaf(pji, wv, zji);
    }
#pragma unroll
    for (int off = 32; off >= 1; off >>= 1) {
        zij += __shfl_xor(zij, off, 64);
        zji += __shfl_xor(zji, off, 64);
    }
    if (lane == 0) {
        float w4f = b2f(W4[0]);
        float b4f = b2f(b4p[0]);
        float d   = zij - zji;                    // b3 cancels exactly
        float vij = fmaf(d, w4f, b4f);  vij = vij > 0.f ? vij : 0.f;
        float vji = fmaf(-d, w4f, b4f); vji = vji > 0.f ? vji : 0.f;
        Vij[gw] = vij;
        Vji[gw] = vji;
        // values >= 0 -> uint-bit ordering == float ordering, 0-init is exact segment max
        atomicMax(maxI + b * NN + src, __float_as_uint(vij));
        atomicMax(maxJ + b * NN + dst, __float_as_uint(vji));
    }
}

// ---------------- softmax pass 2: e = exp(v - m[seg]); segment sums ----------------
__global__ __launch_bounds__(256) void expsum_k(
    float* __restrict__ V,                    // Vij (BE) then Vji (BE)
    const int* __restrict__ eidx,
    const float* __restrict__ maxI, const float* __restrict__ maxJ,
    float* __restrict__ sumI, float* __restrict__ sumJ)
{
    int i = blockIdx.x * 256 + threadIdx.x;
    if (i >= 2 * BE) return;
    int seg; const float* mx; float* sm;
    if (i < BE) {
        int b = i / EE, e = i - b * EE;
        seg = b * NN + eidx[b * 2 * EE + e];
        mx = maxI; sm = sumI;
    } else {
        int j = i - BE;
        int b = j / EE, e = j - b * EE;
        seg = b * NN + eidx[b * 2 * EE + EE + e];
        mx = maxJ; sm = sumJ;
    }
    float v  = V[i];
    float ex = expf(v - mx[seg]);
    V[i] = ex;
    atomicAdd(sm + seg, ex);
}

// ---------------- softmax pass 3: normalize -> bf16 or f32 out ----------------
__global__ __launch_bounds__(256) void norm_k(
    const float* __restrict__ V, const int* __restrict__ eidx,
    const float* __restrict__ sumI, const float* __restrict__ sumJ,
    const int* __restrict__ flag, void* __restrict__ out)
{
    int i = blockIdx.x * 256 + threadIdx.x;
    if (i >= 2 * BE) return;
    int seg; const float* sm;
    if (i < BE) {
        int b = i / EE, e = i - b * EE;
        seg = b * NN + eidx[b * 2 * EE + e];
        sm = sumI;
    } else {
        int j = i - BE;
        int b = j / EE, e = j - b * EE;
        seg = b * NN + eidx[b * 2 * EE + EE + e];
        sm = sumJ;
    }
    float v = V[i] / sm[seg];
    if (*flag) ((float*)out)[i] = v;
    else       ((unsigned short*)out)[i] = f2b(v);
}

extern "C" void kernel_launch(void* const* d_in, const int* in_sizes, int n_in,
                              void* d_out, int out_size, void* d_ws, size_t ws_size,
                              hipStream_t stream)
{
    (void)in_sizes; (void)n_in; (void)out_size; (void)ws_size;
    const void* X_raw = d_in[0];
    const int*  eix   = (const int*)d_in[1];
    const void* W1    = d_in[3];
    const void* b1    = d_in[4];
    const void* g1    = d_in[5];
    const void* bb1   = d_in[6];
    const void* W2    = d_in[7];
    const void* b2    = d_in[8];
    const void* g2    = d_in[9];
    const void* bb2   = d_in[10];
    const void* W3    = d_in[11];
    const void* W4    = d_in[13];
    const void* b4    = d_in[14];

    char* ws = (char*)d_ws;
    size_t off = 0;
    int* flag = (int*)(ws + off);                        off += 16;
    unsigned short* a12 = (unsigned short*)(ws + off);   off += (size_t)M_ROWS * 1024 * 2; // 40.96 MB
    unsigned short* Xb  = (unsigned short*)(ws + off);   off += (size_t)M_PAD * 512 * 2;   // 20.6 MB (padded)
    unsigned short* T1  = (unsigned short*)(ws + off);   off += (size_t)512 * 512 * 2;
    unsigned short* T2  = (unsigned short*)(ws + off);   off += (size_t)512 * 512 * 2;
    unsigned short* P   = (unsigned short*)(ws + off);   off += 8192;
    float* Vbuf = (float*)(ws + off);                    off += (size_t)2 * BE * 4;
    float* Z    = (float*)(ws + off);                    off += (size_t)4 * BB * NN * 4;
    float* maxI = Z;
    float* maxJ = Z + BB * NN;
    float* sumI = Z + 2 * BB * NN;
    float* sumJ = Z + 3 * BB * NN;

    detect_k<<<1, 64, 0, stream>>>((const unsigned short*)X_raw, flag);
    convertX_k<<<(M_ROWS * 512 + 255) / 256, 256, 0, stream>>>(X_raw, flag, Xb, M_ROWS * 512);
    convertP_k<<<15, 256, 0, stream>>>(b1, g1, bb1, b2, g2, bb2, W3, W4, b4, flag, P);
    transpose_k<<<dim3(16, 16, 2), 256, 0, stream>>>(W1, W2, flag, T1, T2);
    zero_k<<<(4 * BB * NN + 255) / 256, 256, 0, stream>>>(Z, 4 * BB * NN);
    gemm_ln2_k<<<dim3(M_PAD / 128, 2), 512, 0, stream>>>(Xb, T1, T2,
                                                         P, P + 512, P + 1024,
                                                         P + 1536, P + 2048, P + 2560, a12);
    edge_k<<<BE / 4, 256, 0, stream>>>(a12, eix, P + 3072, P + 3584, P + 3585,
                                       Vbuf, Vbuf + BE,
                                       (unsigned int*)maxI, (unsigned int*)maxJ);
    expsum_k<<<(2 * BE + 255) / 256, 256, 0, stream>>>(Vbuf, eix, maxI, maxJ, sumI, sumJ);
    norm_k<<<(2 * BE + 255) / 256, 256, 0, stream>>>(Vbuf, eix, sumI, sumJ, flag, (unsigned short*)d_out);
}